// Round 7
// baseline (1032.868 us; speedup 1.0000x reference)
//
#include <hip/hip_runtime.h>
#include <math.h>

#define TT 512
#define BB 128
#define OBSD 512
#define HD 256
#define PD 128
#define LD 4
#define NTB (TT*BB)   // 65536

typedef __bf16 bf16x8 __attribute__((ext_vector_type(8)));
typedef float  f32x4  __attribute__((ext_vector_type(4)));

__device__ __forceinline__ float bf2f(unsigned short u) {
    return __uint_as_float(((unsigned)u) << 16);
}
__device__ __forceinline__ unsigned short f2bf(float f) {
    unsigned u = __float_as_uint(f);
    unsigned r = (u + 0x7FFFu + ((u >> 16) & 1u)) >> 16;
    return (unsigned short)r;
}
__device__ __forceinline__ float gelu_f(float x) {
    float x3 = x * x * x;
    return 0.5f * x * (1.f + tanhf(0.7978845608028654f * (x + 0.044715f * x3)));
}
__device__ __forceinline__ float lane4(float4 v, int r) {
    return (r == 0) ? v.x : (r == 1) ? v.y : (r == 2) ? v.z : v.w;
}

// stage 64x32 bf16 tile (A) into smA, 256 threads, 1 x 16B load each
__device__ __forceinline__ void stgA(const unsigned short* A, int ldk, int m0, int k0,
                                     unsigned short* smA, int tid)
{
    const unsigned short* g = A + (size_t)(m0 + (tid >> 2)) * ldk + k0 + (tid & 3) * 8;
    __builtin_amdgcn_global_load_lds(
        (const __attribute__((address_space(1))) void*)g,
        (__attribute__((address_space(3))) void*)(smA + tid * 8), 16, 0, 0);
}
// stage NR x 32 bf16 tile (B^T rows) into smB, NR in {128,256}
template<int NR>
__device__ __forceinline__ void stgB(const unsigned short* BT, int ldk, int k0,
                                     unsigned short* smB, int tid)
{
#pragma unroll
    for (int p = 0; p < NR / 64; ++p) {
        const unsigned short* g = BT + (size_t)(p * 64 + (tid >> 2)) * ldk + k0 + (tid & 3) * 8;
        __builtin_amdgcn_global_load_lds(
            (const __attribute__((address_space(1))) void*)g,
            (__attribute__((address_space(3))) void*)(smB + p * 2048 + tid * 8), 16, 0, 0);
    }
}

// ============================================================================
// Fused S5 layer kernel. Tile: 64 rows x 256 cols, 256 threads.
// VAR 0 (enc1+Bu0): GEMM1 A=U1@E1T (K1=128): x=leaky(+b); X; LN->u -> zbuf,U
//                   GEMM2 u@BT3(BBAR0) -> BU
// VAR 1 (mid layer): GEMM1 xs@CCAT: v=acc+D*u(aux); LN->gelu->z (regs+zbuf)
//                   GEMM2 z@GLUT: x=X+z*sig(+b2); X; LN2->u -> zbuf,U
//                   GEMM3 u@BT3(BBAR_{l+1}) -> BU
// VAR 2 (last layer): as VAR1 but stop after writing X.
// ============================================================================
template<int VAR>
__global__ __launch_bounds__(256, 2) void fused_k(
    const unsigned short* __restrict__ A, const unsigned short* __restrict__ BT1, int K1,
    const float* __restrict__ bias1, const float* __restrict__ ln1s, const float* __restrict__ ln1b,
    const unsigned short* __restrict__ auxU,
    const unsigned short* __restrict__ BT2, const float* __restrict__ bias2,
    const float* __restrict__ ln2s, const float* __restrict__ ln2b,
    unsigned short* __restrict__ X, unsigned short* __restrict__ Uout,
    const unsigned short* __restrict__ BT3, unsigned short* __restrict__ BU)
{
    const int ZS = 264;                    // zbuf row stride (bf16 elems)
    __shared__ unsigned short smA[64 * 32];
    __shared__ unsigned short smB[256 * 32];
    __shared__ unsigned short zbuf[64 * ZS];
    __shared__ float2 red[64][4];
    int tid = threadIdx.x;
    int lane = tid & 63, w = tid >> 6;
    int m16 = lane & 15, quad = lane >> 4;
    int m0 = blockIdx.x * 64;
    int colb = w * 64 + quad * 4;          // + nj*16

    f32x4 acc[4][4] = {};
    // ---------------- GEMM1 ----------------
    for (int k0 = 0; k0 < K1; k0 += 32) {
        stgA(A, K1, m0, k0, smA, tid);
        stgB<256>(BT1, K1, k0, smB, tid);
        __syncthreads();
        bf16x8 af[4], bfr[4];
#pragma unroll
        for (int mi = 0; mi < 4; ++mi)
            af[mi] = *(const bf16x8*)(smA + (mi * 16 + m16) * 32 + quad * 8);
#pragma unroll
        for (int nj = 0; nj < 4; ++nj)
            bfr[nj] = *(const bf16x8*)(smB + (w * 64 + nj * 16 + m16) * 32 + quad * 8);
#pragma unroll
        for (int mi = 0; mi < 4; ++mi)
#pragma unroll
            for (int nj = 0; nj < 4; ++nj)
                acc[mi][nj] = __builtin_amdgcn_mfma_f32_16x16x32_bf16(
                    bfr[nj], af[mi], acc[mi][nj], 0, 0, 0);
        __syncthreads();
    }

    float4 bn[4];
#pragma unroll
    for (int nj = 0; nj < 4; ++nj) bn[nj] = *(const float4*)(bias1 + colb + nj * 16);

    // ---------------- Epilogue 1: transform + row stats ----------------
#pragma unroll
    for (int mi = 0; mi < 4; ++mi) {
        size_t rowb = (size_t)(m0 + mi * 16 + m16) * 256;
        float s = 0.f, q = 0.f;
#pragma unroll
        for (int nj = 0; nj < 4; ++nj) {
            ushort4 a1;
            if (VAR != 0) a1 = *(const ushort4*)(auxU + rowb + colb + nj * 16);
            float vv[4];
#pragma unroll
            for (int r = 0; r < 4; ++r) {
                float v = acc[mi][nj][r];
                float bv = lane4(bn[nj], r);
                if (VAR == 0) {                     // leaky(acc + b)
                    v += bv; v = v > 0.f ? v : 0.01f * v;
                } else {                            // acc + D[col]*u
                    float uu = bf2f(r == 0 ? a1.x : r == 1 ? a1.y : r == 2 ? a1.z : a1.w);
                    v += bv * uu;
                }
                vv[r] = v; acc[mi][nj][r] = v;
                s += v; q += v * v;
            }
            if (VAR == 0) {                         // x -> X
                ushort4 o = { f2bf(vv[0]), f2bf(vv[1]), f2bf(vv[2]), f2bf(vv[3]) };
                *(ushort4*)(X + rowb + colb + nj * 16) = o;
            }
        }
        s += __shfl_xor(s, 16); q += __shfl_xor(q, 16);
        s += __shfl_xor(s, 32); q += __shfl_xor(q, 32);
        if (quad == 0) red[mi * 16 + m16][w] = float2{s, q};
    }
    __syncthreads();

    // ---------------- E1b: LN (-> u or gelu z), write zbuf ----------------
    float4 l1s[4], l1b[4];
#pragma unroll
    for (int nj = 0; nj < 4; ++nj) {
        l1s[nj] = *(const float4*)(ln1s + colb + nj * 16);
        l1b[nj] = *(const float4*)(ln1b + colb + nj * 16);
    }
#pragma unroll
    for (int mi = 0; mi < 4; ++mi) {
        int row_l = mi * 16 + m16;
        float2 t0 = red[row_l][0], t1 = red[row_l][1], t2 = red[row_l][2], t3 = red[row_l][3];
        float S = t0.x + t1.x + t2.x + t3.x;
        float Q = t0.y + t1.y + t2.y + t3.y;
        float mu = S * (1.f / 256.f);
        float rstd = rsqrtf(Q * (1.f / 256.f) - mu * mu + 1e-6f);
        size_t rowb = (size_t)(m0 + row_l) * 256;
#pragma unroll
        for (int nj = 0; nj < 4; ++nj) {
            float o[4];
#pragma unroll
            for (int r = 0; r < 4; ++r) {
                float v = (acc[mi][nj][r] - mu) * rstd * lane4(l1s[nj], r) + lane4(l1b[nj], r);
                if (VAR != 0) v = gelu_f(v);
                o[r] = v; acc[mi][nj][r] = v;
            }
            ushort4 ov = { f2bf(o[0]), f2bf(o[1]), f2bf(o[2]), f2bf(o[3]) };
            *(ushort4*)(zbuf + row_l * ZS + colb + nj * 16) = ov;
            if (VAR == 0) *(ushort4*)(Uout + rowb + colb + nj * 16) = ov;
        }
    }
    __syncthreads();

    // ---------------- GEMM2 (VAR0: BBAR; VAR1/2: GLUT), A from zbuf --------
    const unsigned short* Bm2 = (VAR == 0) ? BT3 : BT2;
    f32x4 acc2[4][4] = {};
    for (int k0 = 0; k0 < 256; k0 += 32) {
        stgB<256>(Bm2, 256, k0, smB, tid);
        __syncthreads();
        bf16x8 af[4], bfr[4];
#pragma unroll
        for (int mi = 0; mi < 4; ++mi)
            af[mi] = *(const bf16x8*)(zbuf + (mi * 16 + m16) * ZS + k0 + quad * 8);
#pragma unroll
        for (int nj = 0; nj < 4; ++nj)
            bfr[nj] = *(const bf16x8*)(smB + (w * 64 + nj * 16 + m16) * 32 + quad * 8);
#pragma unroll
        for (int mi = 0; mi < 4; ++mi)
#pragma unroll
            for (int nj = 0; nj < 4; ++nj)
                acc2[mi][nj] = __builtin_amdgcn_mfma_f32_16x16x32_bf16(
                    bfr[nj], af[mi], acc2[mi][nj], 0, 0, 0);
        __syncthreads();
    }

    if (VAR == 0) {   // write BU
#pragma unroll
        for (int mi = 0; mi < 4; ++mi) {
            size_t rowb = (size_t)(m0 + mi * 16 + m16) * 256;
#pragma unroll
            for (int nj = 0; nj < 4; ++nj) {
                ushort4 o = { f2bf(acc2[mi][nj][0]), f2bf(acc2[mi][nj][1]),
                              f2bf(acc2[mi][nj][2]), f2bf(acc2[mi][nj][3]) };
                *(ushort4*)(BU + rowb + colb + nj * 16) = o;
            }
        }
        return;
    }

    // ---------------- E2a: GLU + residual, write X, stats ----------------
    float4 b2[4];
#pragma unroll
    for (int nj = 0; nj < 4; ++nj) b2[nj] = *(const float4*)(bias2 + colb + nj * 16);
#pragma unroll
    for (int mi = 0; mi < 4; ++mi) {
        size_t rowb = (size_t)(m0 + mi * 16 + m16) * 256;
        float s = 0.f, q = 0.f;
#pragma unroll
        for (int nj = 0; nj < 4; ++nj) {
            ushort4 xo = *(const ushort4*)(X + rowb + colb + nj * 16);
            float vv[4];
#pragma unroll
            for (int r = 0; r < 4; ++r) {
                float g = acc2[mi][nj][r] + lane4(b2[nj], r);
                float sg = 1.f / (1.f + expf(-g));
                float xx = bf2f(r == 0 ? xo.x : r == 1 ? xo.y : r == 2 ? xo.z : xo.w);
                float v = xx + acc[mi][nj][r] * sg;   // acc holds z
                vv[r] = v; acc2[mi][nj][r] = v;
                s += v; q += v * v;
            }
            ushort4 o = { f2bf(vv[0]), f2bf(vv[1]), f2bf(vv[2]), f2bf(vv[3]) };
            *(ushort4*)(X + rowb + colb + nj * 16) = o;
        }
        if (VAR == 1) {
            s += __shfl_xor(s, 16); q += __shfl_xor(q, 16);
            s += __shfl_xor(s, 32); q += __shfl_xor(q, 32);
            if (quad == 0) red[mi * 16 + m16][w] = float2{s, q};
        }
    }
    if (VAR == 2) return;
    __syncthreads();

    // ---------------- E2b: LN2 -> u_next, write U + zbuf ----------------
    float4 l2s[4], l2b[4];
#pragma unroll
    for (int nj = 0; nj < 4; ++nj) {
        l2s[nj] = *(const float4*)(ln2s + colb + nj * 16);
        l2b[nj] = *(const float4*)(ln2b + colb + nj * 16);
    }
#pragma unroll
    for (int mi = 0; mi < 4; ++mi) {
        int row_l = mi * 16 + m16;
        float2 t0 = red[row_l][0], t1 = red[row_l][1], t2 = red[row_l][2], t3 = red[row_l][3];
        float S = t0.x + t1.x + t2.x + t3.x;
        float Q = t0.y + t1.y + t2.y + t3.y;
        float mu = S * (1.f / 256.f);
        float rstd = rsqrtf(Q * (1.f / 256.f) - mu * mu + 1e-6f);
        size_t rowb = (size_t)(m0 + row_l) * 256;
#pragma unroll
        for (int nj = 0; nj < 4; ++nj) {
            float o[4];
#pragma unroll
            for (int r = 0; r < 4; ++r)
                o[r] = (acc2[mi][nj][r] - mu) * rstd * lane4(l2s[nj], r) + lane4(l2b[nj], r);
            ushort4 ov = { f2bf(o[0]), f2bf(o[1]), f2bf(o[2]), f2bf(o[3]) };
            *(ushort4*)(zbuf + row_l * ZS + colb + nj * 16) = ov;
            *(ushort4*)(Uout + rowb + colb + nj * 16) = ov;
        }
    }
    __syncthreads();

    // ---------------- GEMM3: u_next @ BBAR_{l+1} -> BU ----------------
    f32x4 acc3[4][4] = {};
    for (int k0 = 0; k0 < 256; k0 += 32) {
        stgB<256>(BT3, 256, k0, smB, tid);
        __syncthreads();
        bf16x8 af[4], bfr[4];
#pragma unroll
        for (int mi = 0; mi < 4; ++mi)
            af[mi] = *(const bf16x8*)(zbuf + (mi * 16 + m16) * ZS + k0 + quad * 8);
#pragma unroll
        for (int nj = 0; nj < 4; ++nj)
            bfr[nj] = *(const bf16x8*)(smB + (w * 64 + nj * 16 + m16) * 32 + quad * 8);
#pragma unroll
        for (int mi = 0; mi < 4; ++mi)
#pragma unroll
            for (int nj = 0; nj < 4; ++nj)
                acc3[mi][nj] = __builtin_amdgcn_mfma_f32_16x16x32_bf16(
                    bfr[nj], af[mi], acc3[mi][nj], 0, 0, 0);
        __syncthreads();
    }
#pragma unroll
    for (int mi = 0; mi < 4; ++mi) {
        size_t rowb = (size_t)(m0 + mi * 16 + m16) * 256;
#pragma unroll
        for (int nj = 0; nj < 4; ++nj) {
            ushort4 o = { f2bf(acc3[mi][nj][0]), f2bf(acc3[mi][nj][1]),
                          f2bf(acc3[mi][nj][2]), f2bf(acc3[mi][nj][3]) };
            *(ushort4*)(BU + rowb + colb + nj * 16) = o;
        }
    }
}

// ============ Fused heads: X -> h0 -> h1 -> decoders -> out =================
// grid (1024, 2): y=0 actor branch, y=1 critic branch. Tile 64 x 128.
__global__ __launch_bounds__(256) void head2_k(
    const unsigned short* __restrict__ X,
    const unsigned short* __restrict__ AB0T, const float* __restrict__ ab0_b,
    const unsigned short* __restrict__ AB1T, const float* __restrict__ ab1_b,
    const unsigned short* __restrict__ VB0T, const float* __restrict__ vb0_b,
    const unsigned short* __restrict__ VB1T, const float* __restrict__ vb1_b,
    const float* __restrict__ adW, const float* __restrict__ adb,
    const float* __restrict__ lstd,
    const float* __restrict__ vdW, const float* __restrict__ vdb,
    float* __restrict__ out)
{
    const int HS = 136;
    __shared__ unsigned short smA[64 * 32];
    __shared__ unsigned short smB[128 * 32];
    __shared__ unsigned short hbuf[64 * HS];
    __shared__ float4 redh[64][4];
    int tid = threadIdx.x;
    int lane = tid & 63, w = tid >> 6;
    int m16 = lane & 15, quad = lane >> 4;
    int m0 = blockIdx.x * 64;
    int y = blockIdx.y;
    int colb = w * 32 + quad * 4;          // + nj*16, nj<2

    const unsigned short* BT1 = y ? VB0T : AB0T;
    const unsigned short* BT2 = y ? VB1T : AB1T;
    const float* b0 = y ? vb0_b : ab0_b;
    const float* b1 = y ? vb1_b : ab1_b;

    f32x4 acc[4][2] = {};
    for (int k0 = 0; k0 < 256; k0 += 32) {
        stgA(X, 256, m0, k0, smA, tid);
        stgB<128>(BT1, 256, k0, smB, tid);
        __syncthreads();
        bf16x8 af[4], bfr[2];
#pragma unroll
        for (int mi = 0; mi < 4; ++mi)
            af[mi] = *(const bf16x8*)(smA + (mi * 16 + m16) * 32 + quad * 8);
#pragma unroll
        for (int nj = 0; nj < 2; ++nj)
            bfr[nj] = *(const bf16x8*)(smB + (w * 32 + nj * 16 + m16) * 32 + quad * 8);
#pragma unroll
        for (int mi = 0; mi < 4; ++mi)
#pragma unroll
            for (int nj = 0; nj < 2; ++nj)
                acc[mi][nj] = __builtin_amdgcn_mfma_f32_16x16x32_bf16(
                    bfr[nj], af[mi], acc[mi][nj], 0, 0, 0);
        __syncthreads();
    }
    // h0 = leaky(acc + b0) -> hbuf
#pragma unroll
    for (int mi = 0; mi < 4; ++mi) {
#pragma unroll
        for (int nj = 0; nj < 2; ++nj) {
            float4 bv = *(const float4*)(b0 + colb + nj * 16);
            float o[4];
#pragma unroll
            for (int r = 0; r < 4; ++r) {
                float v = acc[mi][nj][r] + lane4(bv, r);
                o[r] = v > 0.f ? v : 0.01f * v;
            }
            ushort4 ov = { f2bf(o[0]), f2bf(o[1]), f2bf(o[2]), f2bf(o[3]) };
            *(ushort4*)(hbuf + (mi * 16 + m16) * HS + colb + nj * 16) = ov;
        }
    }
    __syncthreads();

    f32x4 acc2[4][2] = {};
    for (int k0 = 0; k0 < 128; k0 += 32) {
        stgB<128>(BT2, 128, k0, smB, tid);
        __syncthreads();
        bf16x8 af[4], bfr[2];
#pragma unroll
        for (int mi = 0; mi < 4; ++mi)
            af[mi] = *(const bf16x8*)(hbuf + (mi * 16 + m16) * HS + k0 + quad * 8);
#pragma unroll
        for (int nj = 0; nj < 2; ++nj)
            bfr[nj] = *(const bf16x8*)(smB + (w * 32 + nj * 16 + m16) * 32 + quad * 8);
#pragma unroll
        for (int mi = 0; mi < 4; ++mi)
#pragma unroll
            for (int nj = 0; nj < 2; ++nj)
                acc2[mi][nj] = __builtin_amdgcn_mfma_f32_16x16x32_bf16(
                    bfr[nj], af[mi], acc2[mi][nj], 0, 0, 0);
        __syncthreads();
    }
    // h1 = leaky(acc2 + b1); decoder partials per row
#pragma unroll
    for (int mi = 0; mi < 4; ++mi) {
        float4 part = {0.f, 0.f, 0.f, 0.f};
#pragma unroll
        for (int nj = 0; nj < 2; ++nj) {
            float4 bv = *(const float4*)(b1 + colb + nj * 16);
#pragma unroll
            for (int r = 0; r < 4; ++r) {
                float v = acc2[mi][nj][r] + lane4(bv, r);
                v = v > 0.f ? v : 0.01f * v;
                int c = colb + nj * 16 + r;
                if (y == 0) {
                    float4 wv = *(const float4*)(adW + c * 4);
                    part.x += v * wv.x; part.y += v * wv.y;
                    part.z += v * wv.z; part.w += v * wv.w;
                } else {
                    part.x += v * vdW[c];
                }
            }
        }
        part.x += __shfl_xor(part.x, 16); part.x += __shfl_xor(part.x, 32);
        part.y += __shfl_xor(part.y, 16); part.y += __shfl_xor(part.y, 32);
        part.z += __shfl_xor(part.z, 16); part.z += __shfl_xor(part.z, 32);
        part.w += __shfl_xor(part.w, 16); part.w += __shfl_xor(part.w, 32);
        if (quad == 0) redh[mi * 16 + m16][w] = part;
    }
    __syncthreads();
    if (tid < 64) {
        float4 t0 = redh[tid][0], t1 = redh[tid][1], t2 = redh[tid][2], t3 = redh[tid][3];
        size_t o = (size_t)(m0 + tid) * 9;
        if (y == 0) {
            out[o + 0] = t0.x + t1.x + t2.x + t3.x + adb[0];
            out[o + 1] = t0.y + t1.y + t2.y + t3.y + adb[1];
            out[o + 2] = t0.z + t1.z + t2.z + t3.z + adb[2];
            out[o + 3] = t0.w + t1.w + t2.w + t3.w + adb[3];
#pragma unroll
            for (int a = 0; a < 4; ++a) out[o + 4 + a] = expf(lstd[a]);
        } else {
            out[o + 8] = t0.x + t1.x + t2.x + t3.x + vdb[0];
        }
    }
}

// ======= enc0: A f32 (obs), staged to bf16 LDS in VGPRs; tile 64x128 ========
__global__ __launch_bounds__(256) void mgemm_obs(
    const float* __restrict__ A, const unsigned short* __restrict__ BT,
    unsigned short* __restrict__ U, const float* __restrict__ bias)
{
    const int K = 512, NJ = 2, N = 128;
    __shared__ unsigned short smA[64 * 32];
    __shared__ unsigned short smB[NJ * 64 * 32];
    int tid = threadIdx.x;
    int lane = tid & 63, w = tid >> 6;
    int m16 = lane & 15, quad = lane >> 4;
    int m0 = blockIdx.x * 64;

    f32x4 acc[4][NJ] = {};
    for (int k0 = 0; k0 < K; k0 += 32) {
#pragma unroll
        for (int p = 0; p < 2; ++p) {
            int idx = p * 256 + tid;
            int r = idx >> 3, kq = (idx & 7) * 4;
            float4 v = *(const float4*)(A + (size_t)(m0 + r) * K + k0 + kq);
            ushort4 o = { f2bf(v.x), f2bf(v.y), f2bf(v.z), f2bf(v.w) };
            *(ushort4*)(smA + r * 32 + kq) = o;
        }
        stgB<128>(BT, K, k0, smB, tid);
        __syncthreads();
        bf16x8 af[4], bfr[NJ];
#pragma unroll
        for (int mi = 0; mi < 4; ++mi)
            af[mi] = *(const bf16x8*)(smA + (mi * 16 + m16) * 32 + quad * 8);
#pragma unroll
        for (int nj = 0; nj < NJ; ++nj)
            bfr[nj] = *(const bf16x8*)(smB + (w * NJ * 16 + nj * 16 + m16) * 32 + quad * 8);
#pragma unroll
        for (int mi = 0; mi < 4; ++mi)
#pragma unroll
            for (int nj = 0; nj < NJ; ++nj)
                acc[mi][nj] = __builtin_amdgcn_mfma_f32_16x16x32_bf16(
                    bfr[nj], af[mi], acc[mi][nj], 0, 0, 0);
        __syncthreads();
    }
    int colb = w * NJ * 16 + quad * 4;
#pragma unroll
    for (int mi = 0; mi < 4; ++mi) {
        size_t rowb = (size_t)(m0 + mi * 16 + m16) * N;
#pragma unroll
        for (int nj = 0; nj < NJ; ++nj) {
            float4 bv = *(const float4*)(bias + colb + nj * 16);
            float v0 = acc[mi][nj][0] + bv.x; v0 = v0 > 0.f ? v0 : 0.01f * v0;
            float v1 = acc[mi][nj][1] + bv.y; v1 = v1 > 0.f ? v1 : 0.01f * v1;
            float v2 = acc[mi][nj][2] + bv.z; v2 = v2 > 0.f ? v2 : 0.01f * v2;
            float v3 = acc[mi][nj][3] + bv.w; v3 = v3 > 0.f ? v3 : 0.01f * v3;
            ushort4 o = { f2bf(v0), f2bf(v1), f2bf(v2), f2bf(v3) };
            *(ushort4*)(U + rowb + colb + nj * 16) = o;
        }
    }
}

// ------------- Chunk-parallel scan, interleaved (re,im) packing -------------
__global__ __launch_bounds__(512) void scan2_k(
    const unsigned short* __restrict__ bu, unsigned short* __restrict__ xs,
    const float* __restrict__ dones,
    const float* __restrict__ h0re, const float* __restrict__ h0im,
    const float* __restrict__ lamre, const float* __restrict__ lamim,
    const float* __restrict__ lstep,
    float* __restrict__ outre, float* __restrict__ outim)
{
    __shared__ float sdone[TT];
    __shared__ float4 ssum[8][64];
    __shared__ float2 shin[8][64];
    int tid = threadIdx.x;
    int b  = blockIdx.x >> 1;
    int ph = blockIdx.x & 1;
    int chunk = tid >> 6, pl = tid & 63;
    int p = ph * 64 + pl;
    sdone[tid] = dones[tid * BB + b];
    float lr = lamre[p], li = lamim[p];
    float st = expf(lstep[p]);
    float er = expf(lr * st);
    float ar = er * cosf(li * st);
    float ai = er * sinf(li * st);
    __syncthreads();

    int t0 = chunk * 64;
    unsigned buf[64];
    float Ar = 1.f, Ai = 0.f, br = 0.f, bi = 0.f;
#pragma unroll
    for (int j = 0; j < 64; ++j) {
        size_t off = ((size_t)(t0 + j) * BB + b) * 256 + 2 * p;
        unsigned v = *(const unsigned*)(bu + off);
        buf[j] = v;
        float bur = bf2f((unsigned short)(v & 0xFFFFu));
        float bui = bf2f((unsigned short)(v >> 16));
        if (sdone[t0 + j] != 0.f) {
            Ar = 0.f; Ai = 0.f; br = bur; bi = bui;
        } else {
            float nAr = ar * Ar - ai * Ai;
            float nAi = ar * Ai + ai * Ar;
            float nbr = fmaf(ar, br, fmaf(-ai, bi, bur));
            float nbi = fmaf(ar, bi, fmaf(ai, br, bui));
            Ar = nAr; Ai = nAi; br = nbr; bi = nbi;
        }
    }
    ssum[chunk][pl] = float4{Ar, Ai, br, bi};
    __syncthreads();
    if (tid < 64) {
        int gid = b * 128 + p;
        float hr = h0re[gid], hi = h0im[gid];
#pragma unroll
        for (int c = 0; c < 8; ++c) {
            shin[c][pl] = float2{hr, hi};
            float4 s = ssum[c][pl];
            float nhr = fmaf(s.x, hr, fmaf(-s.y, hi, s.z));
            float nhi = fmaf(s.x, hi, fmaf(s.y, hr, s.w));
            hr = nhr; hi = nhi;
        }
        outre[gid] = hr; outim[gid] = hi;
    }
    __syncthreads();
    float hr = shin[chunk][pl].x, hi = shin[chunk][pl].y;
#pragma unroll
    for (int j = 0; j < 64; ++j) {
        unsigned v = buf[j];
        float bur = bf2f((unsigned short)(v & 0xFFFFu));
        float bui = bf2f((unsigned short)(v >> 16));
        float nr, ni;
        if (sdone[t0 + j] != 0.f) { nr = bur; ni = bui; }
        else {
            nr = fmaf(ar, hr, fmaf(-ai, hi, bur));
            ni = fmaf(ar, hi, fmaf(ai, hr, bui));
        }
        hr = nr; hi = ni;
        size_t off = ((size_t)(t0 + j) * BB + b) * 256 + 2 * p;
        *(unsigned*)(xs + off) = ((unsigned)f2bf(ni) << 16) | f2bf(nr);
    }
}

// -- Precompute B_barT (interleaved n: 2p/2p+1) and CcatT (interleaved k) ----
__global__ __launch_bounds__(256) void prep_k(
    const float* __restrict__ Br, const float* __restrict__ Bi,
    const float* __restrict__ Cr, const float* __restrict__ Ci,
    const float* __restrict__ Lr, const float* __restrict__ Li,
    const float* __restrict__ ls, unsigned short* bbarT, unsigned short* ccatT)
{
    int gid = blockIdx.x * 256 + threadIdx.x;   // L*P*H = 131072
    int l = gid >> 15;
    int rem = gid & 32767;
    int p = rem >> 8;
    int h = rem & 255;
    float lr = Lr[l * PD + p], li = Li[l * PD + p];
    float st = expf(ls[l * PD + p]);
    float er = expf(lr * st);
    float lbr = er * cosf(li * st);
    float lbi = er * sinf(li * st);
    float nr = lbr - 1.f, ni = lbi;
    float den = lr * lr + li * li;
    float fr = (nr * lr + ni * li) / den;
    float fi = (ni * lr - nr * li) / den;
    float bre = Br[(size_t)(l * PD + p) * HD + h];
    float bim = Bi[(size_t)(l * PD + p) * HD + h];
    size_t lb = (size_t)l * 65536;
    bbarT[lb + (size_t)(2 * p) * 256 + h]     = f2bf(fr * bre - fi * bim);
    bbarT[lb + (size_t)(2 * p + 1) * 256 + h] = f2bf(fr * bim + fi * bre);
    float cre = Cr[(size_t)(l * HD + h) * PD + p];
    float cim = Ci[(size_t)(l * HD + h) * PD + p];
    ccatT[lb + (size_t)h * 256 + 2 * p]     = f2bf(2.f * cre);
    ccatT[lb + (size_t)h * 256 + 2 * p + 1] = f2bf(-2.f * cim);
}

// -------- all weight transposes (f32 [K][N] -> bf16 [N][K]) in one launch ---
__global__ __launch_bounds__(256) void tcvt_all(
    const float* __restrict__ e0, const float* __restrict__ e1,
    const float* __restrict__ glu, const float* __restrict__ a0,
    const float* __restrict__ a1, const float* __restrict__ v0,
    const float* __restrict__ v1,
    unsigned short* E0T, unsigned short* E1T, unsigned short* GLUT,
    unsigned short* AB0T, unsigned short* AB1T, unsigned short* VB0T,
    unsigned short* VB1T)
{
    int gid = blockIdx.x * 256 + threadIdx.x;   // total 458752
    const float* in; unsigned short* outp; int K, N, local;
    if (gid < 65536)       { in = e0; outp = E0T; K = 512; N = 128; local = gid; }
    else if (gid < 98304)  { in = e1; outp = E1T; K = 128; N = 256; local = gid - 65536; }
    else if (gid < 360448) { local = gid - 98304; int l = local >> 16; local &= 65535;
                             in = glu + (size_t)l * 65536; outp = GLUT + (size_t)l * 65536; K = 256; N = 256; }
    else if (gid < 393216) { in = a0; outp = AB0T; K = 256; N = 128; local = gid - 360448; }
    else if (gid < 409600) { in = a1; outp = AB1T; K = 128; N = 128; local = gid - 393216; }
    else if (gid < 442368) { in = v0; outp = VB0T; K = 256; N = 128; local = gid - 409600; }
    else                   { in = v1; outp = VB1T; K = 128; N = 128; local = gid - 442368; }
    int k = local / N, n = local - k * N;
    outp[(size_t)n * K + k] = f2bf(in[local]);
}

extern "C" void kernel_launch(void* const* d_in, const int* in_sizes, int n_in,
                              void* d_out, int out_size, void* d_ws, size_t ws_size,
                              hipStream_t stream) {
    (void)in_sizes; (void)n_in; (void)out_size; (void)ws_size;
    const float* obs     = (const float*)d_in[0];
    const float* dones   = (const float*)d_in[1];
    const float* hre     = (const float*)d_in[2];
    const float* him     = (const float*)d_in[3];
    const float* enc0_W  = (const float*)d_in[4];
    const float* enc0_b  = (const float*)d_in[5];
    const float* enc1_W  = (const float*)d_in[6];
    const float* enc1_b  = (const float*)d_in[7];
    const float* nsc     = (const float*)d_in[8];
    const float* nbi     = (const float*)d_in[9];
    const float* Lre     = (const float*)d_in[10];
    const float* Lim     = (const float*)d_in[11];
    const float* B_re    = (const float*)d_in[12];
    const float* B_im    = (const float*)d_in[13];
    const float* C_re    = (const float*)d_in[14];
    const float* C_im    = (const float*)d_in[15];
    const float* Dv      = (const float*)d_in[16];
    const float* lstep   = (const float*)d_in[17];
    const float* glu_W   = (const float*)d_in[18];
    const float* glu_b   = (const float*)d_in[19];
    const float* ab0_W   = (const float*)d_in[20];
    const float* ab0_b   = (const float*)d_in[21];
    const float* ab1_W   = (const float*)d_in[22];
    const float* ab1_b   = (const float*)d_in[23];
    const float* adec_W  = (const float*)d_in[24];
    const float* adec_b  = (const float*)d_in[25];
    const float* log_std = (const float*)d_in[26];
    const float* vb0_W   = (const float*)d_in[27];
    const float* vb0_b   = (const float*)d_in[28];
    const float* vb1_W   = (const float*)d_in[29];
    const float* vb1_b   = (const float*)d_in[30];
    const float* vdec_W  = (const float*)d_in[31];
    const float* vdec_b  = (const float*)d_in[32];

    const size_t MB = (size_t)1 << 20;
    char* wsb = (char*)d_ws;
    unsigned short* XS    = (unsigned short*)(wsb);              // 32MB xs
    unsigned short* U1    = (unsigned short*)(wsb + 64 * MB);    // 16MB enc0 out
    unsigned short* X     = (unsigned short*)(wsb + 96 * MB);    // 32MB residual
    unsigned short* U     = (unsigned short*)(wsb + 128 * MB);   // 32MB u
    unsigned short* BU    = (unsigned short*)(wsb + 160 * MB);   // 32MB Bu
    char* wgt = wsb + 192 * MB;
    unsigned short* BBART = (unsigned short*)(wgt);              // 512KB
    unsigned short* CCATT = (unsigned short*)(wgt + 512 * 1024);
    unsigned short* GLUT  = (unsigned short*)(wgt + 1024 * 1024);
    unsigned short* E0T   = (unsigned short*)(wgt + 1536 * 1024);
    unsigned short* E1T   = (unsigned short*)(wgt + 1664 * 1024);
    unsigned short* AB0T  = (unsigned short*)(wgt + 1728 * 1024);
    unsigned short* AB1T  = (unsigned short*)(wgt + 1792 * 1024);
    unsigned short* VB0T  = (unsigned short*)(wgt + 1824 * 1024);
    unsigned short* VB1T  = (unsigned short*)(wgt + 1888 * 1024);

    float* out   = (float*)d_out;
    float* outre = out + (size_t)NTB * 9;
    float* outim = outre + LD * BB * PD;

    // ---- weight prep (2 launches) ----
    prep_k<<<512, 256, 0, stream>>>(B_re, B_im, C_re, C_im, Lre, Lim, lstep, BBART, CCATT);
    tcvt_all<<<1792, 256, 0, stream>>>(enc0_W, enc1_W, glu_W, ab0_W, ab1_W, vb0_W, vb1_W,
                                       E0T, E1T, GLUT, AB0T, AB1T, VB0T, VB1T);

    // ---- encoder ----
    mgemm_obs<<<1024, 256, 0, stream>>>(obs, E0T, U1, enc0_b);
    // enc1 + LN0 + Bu0 fused
    fused_k<0><<<1024, 256, 0, stream>>>(U1, E1T, 128, enc1_b, nsc, nbi,
                                         nullptr, nullptr, nullptr, nullptr, nullptr,
                                         X, U, BBART, BU);

    // ---- S5 layers: scan + fused(ys+GLU+Bu_next) ----
    for (int l = 0; l < LD; ++l) {
        scan2_k<<<256, 512, 0, stream>>>(BU, XS, dones, hre + l * BB * PD, him + l * BB * PD,
                                         Lre + l * PD, Lim + l * PD, lstep + l * PD,
                                         outre + l * BB * PD, outim + l * BB * PD);
        if (l < LD - 1) {
            fused_k<1><<<1024, 256, 0, stream>>>(XS, CCATT + (size_t)l * 65536, 256,
                Dv + l * HD, nsc + l * HD, nbi + l * HD, U,
                GLUT + (size_t)l * 65536, glu_b + l * HD,
                nsc + (l + 1) * HD, nbi + (l + 1) * HD,
                X, U, BBART + (size_t)(l + 1) * 65536, BU);
        } else {
            fused_k<2><<<1024, 256, 0, stream>>>(XS, CCATT + (size_t)l * 65536, 256,
                Dv + l * HD, nsc + l * HD, nbi + l * HD, U,
                GLUT + (size_t)l * 65536, glu_b + l * HD,
                nullptr, nullptr,
                X, nullptr, nullptr, nullptr);
        }
    }

    // ---- heads (fused both branches + decoders) ----
    head2_k<<<dim3(1024, 2), 256, 0, stream>>>(X, AB0T, ab0_b, AB1T, ab1_b,
                                               VB0T, vb0_b, VB1T, vb1_b,
                                               adec_W, adec_b, log_std, vdec_W, vdec_b, out);
}